// Round 13
// baseline (399.653 us; speedup 1.0000x reference)
//
#include <hip/hip_runtime.h>
#include <hip/hip_bf16.h>

#define NN 16384
#define EE 524288

constexpr int D0 = 256, D1 = 128, D2 = 64;

typedef __attribute__((ext_vector_type(8))) short short8;
typedef __attribute__((ext_vector_type(4))) float f32x4;

__device__ __forceinline__ float b2f(ushort u) {
  union { unsigned int i; float f; } x;
  x.i = ((unsigned int)u) << 16;
  return x.f;
}
__device__ __forceinline__ ushort f2b(float f) {
  __hip_bfloat16 h = __float2bfloat16(f);
  return *reinterpret_cast<ushort*>(&h);
}

// ---------------- degree / CSR build ----------------

__global__ __launch_bounds__(256) void count_deg_kernel(
    const int* __restrict__ src, const int* __restrict__ dst,
    int* __restrict__ deg_out, int* __restrict__ deg_in) {
  int e = blockIdx.x * 256 + threadIdx.x;
  if (e < EE) {
    atomicAdd(&deg_out[src[e]], 1);
    atomicAdd(&deg_in[dst[e]], 1);
  }
}

// single-kernel scan: 1 block x 1024 threads, 16 nodes/thread.
// Produces row_ptr, cursor, and both norms (fuses old norm kernel).
__global__ __launch_bounds__(1024) void scan_all_kernel(
    const int* __restrict__ deg_in, const int* __restrict__ deg_out,
    int* __restrict__ row_ptr, int* __restrict__ cursor,
    float* __restrict__ norm_out, float* __restrict__ norm_in) {
  __shared__ int part[1024];
  int t = threadIdx.x;
  int base = t * 16;
  int loc[16];
  int s = 0;
#pragma unroll
  for (int j = 0; j < 16; ++j) { loc[j] = deg_in[base + j]; s += loc[j]; }
  part[t] = s;
  __syncthreads();
  for (int off = 1; off < 1024; off <<= 1) {
    int add = (t >= off) ? part[t - off] : 0;
    __syncthreads();
    part[t] += add;
    __syncthreads();
  }
  int run = (t == 0) ? 0 : part[t - 1];
#pragma unroll
  for (int j = 0; j < 16; ++j) {
    row_ptr[base + j] = run;
    cursor[base + j] = run;
    norm_in[base + j] = rsqrtf(fmaxf((float)loc[j], 1.0f));
    norm_out[base + j] = rsqrtf(fmaxf((float)deg_out[base + j], 1.0f));
    run += loc[j];
  }
  if (t == 1023) row_ptr[NN] = run;
}

__global__ __launch_bounds__(256) void fill_csr_kernel(
    const int* __restrict__ src, const int* __restrict__ dst,
    int* __restrict__ cursor, int* __restrict__ csr_src) {
  int e = blockIdx.x * 256 + threadIdx.x;
  if (e < EE) {
    int pos = atomicAdd(&cursor[dst[e]], 1);
    csr_src[pos] = src[e];
  }
}

// ---------------- dense GEMM: t = (h o norm_out) @ W ----------------
// 32 rows/block; A + W-chunk in LDS. INBF16: h is bf16.

template<int DIN, int DOUT, int KC, bool INBF16>
__global__ __launch_bounds__(256) void gemm_kernel(
    const void* __restrict__ hp, const float* __restrict__ W,
    const float* __restrict__ norm_out, ushort* __restrict__ tb) {
  constexpr int W4 = DOUT / 4;   // 32 or 16
  constexpr int RG = 256 / W4;   // 8 or 16 row-groups
  constexpr int RPT = 32 / RG;   // rows per thread: 4 or 2
  __shared__ float A[32][DIN];
  __shared__ float WC[KC][DOUT];
  int tid = threadIdx.x;
  int r0 = blockIdx.x * 32;
  if (INBF16) {
    constexpr int NF8 = 32 * DIN / 8;
    for (int q = tid; q < NF8; q += 256) {
      int r = q / (DIN / 8);
      int c = q % (DIN / 8);
      short8 m = *(const short8*)((const ushort*)hp + (size_t)(r0 + r) * DIN + c * 8);
      float no = norm_out[r0 + r];
#pragma unroll
      for (int i = 0; i < 8; ++i) A[r][c * 8 + i] = b2f((ushort)m[i]) * no;
    }
  } else {
    constexpr int NF4 = 32 * DIN / 4;
    for (int q = tid; q < NF4; q += 256) {
      int r = q / (DIN / 4);
      int c = q % (DIN / 4);
      float4 x = *(const float4*)((const float*)hp + (size_t)(r0 + r) * DIN + c * 4);
      float no = norm_out[r0 + r];
      x.x *= no; x.y *= no; x.z *= no; x.w *= no;
      *(float4*)&A[r][c * 4] = x;
    }
  }
  int c4 = tid % W4;
  int rg = tid / W4;
  float4 acc[RPT];
#pragma unroll
  for (int j = 0; j < RPT; ++j) acc[j] = make_float4(0.f, 0.f, 0.f, 0.f);

  for (int kc = 0; kc < DIN / KC; ++kc) {
    __syncthreads();
#pragma unroll
    for (int q = 0; q < KC * W4 / 256; ++q)
      ((float4*)WC)[q * 256 + tid] =
          ((const float4*)W)[(size_t)kc * KC * W4 + q * 256 + tid];
    __syncthreads();
#pragma unroll 4
    for (int k2 = 0; k2 < KC; ++k2) {
      float4 w = *(const float4*)&WC[k2][c4 * 4];
#pragma unroll
      for (int j = 0; j < RPT; ++j) {
        float a = A[rg + j * RG][kc * KC + k2];
        acc[j].x += a * w.x; acc[j].y += a * w.y;
        acc[j].z += a * w.z; acc[j].w += a * w.w;
      }
    }
  }
#pragma unroll
  for (int j = 0; j < RPT; ++j) {
    size_t row = (size_t)(r0 + rg + j * RG);
    ushort4 o;
    o.x = f2b(acc[j].x); o.y = f2b(acc[j].y);
    o.z = f2b(acc[j].z); o.w = f2b(acc[j].w);
    *(ushort4*)&tb[row * DOUT + c4 * 4] = o;
  }
}

// ---------------- gather: one node/block, csr staged in LDS, 2x MLP -----
// out[v] = act(norm_in[v] * sum_src t[src] + b). bf16 in; bf16 out
// (+ optional fp32 z for the final layer).

template<int DOUT, bool RELU, bool WRITEZ>
__global__ __launch_bounds__(256) void gather_kernel(
    const ushort* __restrict__ t, const float* __restrict__ bias,
    const float* __restrict__ norm_in, const int* __restrict__ row_ptr,
    const int* __restrict__ csr, ushort* __restrict__ outb,
    float* __restrict__ zout) {
  constexpr int G8 = DOUT / 8;   // 16 (D=128) or 8 (D=64)
  constexpr int S = 256 / G8;    // 16 or 32 edge slots
  __shared__ float red[S][G8][8];
  __shared__ int ecsr[256];
  int tid = threadIdx.x;
  int c8 = tid % G8, slot = tid / G8;
  int v = blockIdx.x;
  int k0 = row_ptr[v], k1 = row_ptr[v + 1];
  int nk = k1 - k0;
  if (tid < nk && tid < 256) ecsr[tid] = csr[k0 + tid];
  __syncthreads();
  float a[8];
#pragma unroll
  for (int i = 0; i < 8; ++i) a[i] = 0.f;
  for (int k = slot; k < nk; k += 2 * S) {
    int s0 = (k < 256) ? ecsr[k] : csr[k0 + k];
    int kb = k + S;
    bool h2 = kb < nk;
    int s1 = h2 ? ((kb < 256) ? ecsr[kb] : csr[k0 + kb]) : s0;
    short8 m0 = *(const short8*)&t[(size_t)s0 * DOUT + c8 * 8];
    short8 m1 = *(const short8*)&t[(size_t)s1 * DOUT + c8 * 8];
#pragma unroll
    for (int i = 0; i < 8; ++i) a[i] += b2f((ushort)m0[i]);
    if (h2) {
#pragma unroll
      for (int i = 0; i < 8; ++i) a[i] += b2f((ushort)m1[i]);
    }
  }
#pragma unroll
  for (int i = 0; i < 8; ++i) red[slot][c8][i] = a[i];
  __syncthreads();
#pragma unroll
  for (int s = S / 2; s >= 1; s >>= 1) {
    if (slot < s) {
#pragma unroll
      for (int i = 0; i < 8; ++i) red[slot][c8][i] += red[slot + s][c8][i];
    }
    __syncthreads();
  }
  if (tid < G8) {
    float ni = norm_in[v];
    float o[8];
#pragma unroll
    for (int i = 0; i < 8; ++i) {
      o[i] = red[0][tid][i] * ni + bias[tid * 8 + i];
      if (RELU) o[i] = fmaxf(o[i], 0.f);
    }
    ushort4 b0, b1;
    b0.x = f2b(o[0]); b0.y = f2b(o[1]); b0.z = f2b(o[2]); b0.w = f2b(o[3]);
    b1.x = f2b(o[4]); b1.y = f2b(o[5]); b1.z = f2b(o[6]); b1.w = f2b(o[7]);
    ushort* op = outb + (size_t)v * DOUT + tid * 8;
    *(ushort4*)op = b0;
    *(ushort4*)(op + 4) = b1;
    if (WRITEZ) {
      float* zp = zout + (size_t)v * DOUT + tid * 8;
      *(float4*)zp = make_float4(o[0], o[1], o[2], o[3]);
      *(float4*)(zp + 4) = make_float4(o[4], o[5], o[6], o[7]);
    }
  }
}

// ---------------- adjacency: C = sigmoid(zb @ zb^T) via bf16 MFMA --------
// R8-proven: 128x128 tile, operand-swapped MFMA, LDS-transpose epilogue.

__global__ __launch_bounds__(256) void adj_mfma_kernel(
    const ushort* __restrict__ zb, float* __restrict__ C) {
  __shared__ ushort SMEM[2 * 128 * 64];  // 32 KB: staging, then epilogue scratch
  ushort* ZR = SMEM;
  ushort* ZC = SMEM + 128 * 64;
  int t = threadIdx.x;
  int bx = blockIdx.x & 127, by = blockIdx.x >> 7;
  int row0 = by * 128, col0 = bx * 128;
  {
    int r = t >> 1;
    int ub = (t & 1) * 4;
    const float4* zr = (const float4*)(zb + (size_t)(row0 + r) * 64);
    const float4* zc = (const float4*)(zb + (size_t)(col0 + r) * 64);
    float4* LR = (float4*)ZR;
    float4* LC = (float4*)ZC;
#pragma unroll
    for (int u = 0; u < 4; ++u) {
      int sw = (ub + u) ^ (r & 7);
      LR[r * 8 + sw] = zr[ub + u];
      LC[r * 8 + sw] = zc[ub + u];
    }
  }
  __syncthreads();
  int l = t & 63, w = t >> 6;
  int wy = w >> 1, wx = w & 1;
  int lr = l & 15, lg = l >> 4;
  f32x4 acc[4][4];
#pragma unroll
  for (int i = 0; i < 4; ++i)
#pragma unroll
    for (int j = 0; j < 4; ++j) acc[i][j] = (f32x4){0.f, 0.f, 0.f, 0.f};

#pragma unroll
  for (int ks = 0; ks < 2; ++ks) {
    short8 af[4], bf_[4];
    int u = ks * 4 + lg;
#pragma unroll
    for (int i = 0; i < 4; ++i) {
      int ar = wy * 64 + i * 16 + lr;
      af[i] = *(const short8*)&ZR[ar * 64 + ((u ^ (ar & 7)) << 3)];
      int ac = wx * 64 + i * 16 + lr;
      bf_[i] = *(const short8*)&ZC[ac * 64 + ((u ^ (ac & 7)) << 3)];
    }
    // swapped operands: n'=lane&15 -> C-row, m'=(lane>>4)*4+reg -> C-col
#pragma unroll
    for (int i = 0; i < 4; ++i)
#pragma unroll
      for (int j = 0; j < 4; ++j)
        acc[i][j] = __builtin_amdgcn_mfma_f32_16x16x32_bf16(
            bf_[j], af[i], acc[i][j], 0, 0, 0);
  }

  // ---- epilogue: per-wave LDS transpose, coalesced row stores ----
  __syncthreads();
  float* scr = ((float*)SMEM) + w * (16 * 68);  // per-wave 16x68 f32
  int sr = l >> 4;            // 0..3
  int sc = (l & 15) * 4;      // 0..60
  float* Cbase = C + (size_t)(row0 + wy * 64) * NN + col0 + wx * 64 + sc;
#pragma unroll
  for (int i = 0; i < 4; ++i) {
#pragma unroll
    for (int j = 0; j < 4; ++j) {
      f32x4 o;
      o[0] = __builtin_amdgcn_rcpf(1.0f + __expf(-acc[i][j][0]));
      o[1] = __builtin_amdgcn_rcpf(1.0f + __expf(-acc[i][j][1]));
      o[2] = __builtin_amdgcn_rcpf(1.0f + __expf(-acc[i][j][2]));
      o[3] = __builtin_amdgcn_rcpf(1.0f + __expf(-acc[i][j][3]));
      *(f32x4*)&scr[lr * 68 + j * 16 + lg * 4] = o;
    }
    __syncthreads();
#pragma unroll
    for (int rp = 0; rp < 4; ++rp) {
      int rloc = rp * 4 + sr;
      float4 v = *(const float4*)&scr[rloc * 68 + sc];
      *(float4*)&Cbase[(size_t)(i * 16 + rloc) * NN] = v;
    }
    __syncthreads();
  }
}

// ---------------- launch ----------------

extern "C" void kernel_launch(void* const* d_in, const int* in_sizes, int n_in,
                              void* d_out, int out_size, void* d_ws, size_t ws_size,
                              hipStream_t stream) {
  const float* features = (const float*)d_in[0];
  const int* src = (const int*)d_in[1];
  const int* dst = (const int*)d_in[2];
  const float* W1 = (const float*)d_in[3];
  const float* b1 = (const float*)d_in[4];
  const float* W2 = (const float*)d_in[5];
  const float* b2 = (const float*)d_in[6];
  const float* W3 = (const float*)d_in[7];
  const float* b3 = (const float*)d_in[8];

  float* outp = (float*)d_out;
  float* adj = outp;                      // [N, N]
  float* z = outp + (size_t)NN * NN;      // [N, 64]

  // scratch inside adj — all DEAD before adj_mfma launches:
  ushort* tb = (ushort*)adj;              // N*128 bf16 (4 MB): t1/t2/t3
  ushort* hb = (ushort*)(adj + (size_t)NN * 64);  // N*128 bf16: h1/h2

  float* wsf = (float*)d_ws;
  float* norm_out = wsf;                  // N
  float* norm_in = wsf + NN;              // N
  int* deg_out = (int*)(wsf + 2 * NN);    // N
  int* deg_in = deg_out + NN;             // N
  int* row_ptr = deg_in + NN;             // N+1 (+pad)
  int* cursor = row_ptr + NN + 256;       // N
  int* csr_src = cursor + NN;             // E
  ushort* zb = (ushort*)(csr_src + EE);   // N*64 bf16 — in d_ws (adj reads it)

  hipMemsetAsync(deg_out, 0, 2 * NN * sizeof(int), stream);
  count_deg_kernel<<<EE / 256, 256, 0, stream>>>(src, dst, deg_out, deg_in);
  scan_all_kernel<<<1, 1024, 0, stream>>>(deg_in, deg_out, row_ptr, cursor,
                                          norm_out, norm_in);
  fill_csr_kernel<<<EE / 256, 256, 0, stream>>>(src, dst, cursor, csr_src);

  // layer 1: t1 = (x o n)W1 (bf16); h1 = relu(agg o n_in + b1) (bf16)
  gemm_kernel<D0, D1, 32, false><<<NN / 32, 256, 0, stream>>>(
      features, W1, norm_out, tb);
  gather_kernel<D1, true, false><<<NN, 256, 0, stream>>>(
      tb, b1, norm_in, row_ptr, csr_src, hb, nullptr);
  // layer 2
  gemm_kernel<D1, D1, 64, true><<<NN / 32, 256, 0, stream>>>(
      hb, W2, norm_out, tb);
  gather_kernel<D1, true, false><<<NN, 256, 0, stream>>>(
      tb, b2, norm_in, row_ptr, csr_src, hb, nullptr);
  // layer 3 (no relu): t3 bf16; gather writes zb bf16 + z fp32
  gemm_kernel<D1, D2, 64, true><<<NN / 32, 256, 0, stream>>>(
      hb, W3, norm_out, tb);
  gather_kernel<D2, false, true><<<NN, 256, 0, stream>>>(
      tb, b3, norm_in, row_ptr, csr_src, zb, z);

  adj_mfma_kernel<<<(NN / 128) * (NN / 128), 256, 0, stream>>>(zb, adj);
}

// Round 14
// 394.038 us; speedup vs baseline: 1.0142x; 1.0142x over previous
//
#include <hip/hip_runtime.h>
#include <hip/hip_bf16.h>

#define NN 16384
#define EE 524288

constexpr int D0 = 256, D1 = 128, D2 = 64;

typedef __attribute__((ext_vector_type(8))) short short8;
typedef __attribute__((ext_vector_type(4))) float f32x4;

__device__ __forceinline__ float b2f(ushort u) {
  union { unsigned int i; float f; } x;
  x.i = ((unsigned int)u) << 16;
  return x.f;
}
__device__ __forceinline__ ushort f2b(float f) {
  __hip_bfloat16 h = __float2bfloat16(f);
  return *reinterpret_cast<ushort*>(&h);
}

// ---------------- degree / CSR build ----------------

__global__ __launch_bounds__(256) void count_deg_kernel(
    const int* __restrict__ src, const int* __restrict__ dst,
    int* __restrict__ deg_out, int* __restrict__ deg_in) {
  int e = blockIdx.x * 256 + threadIdx.x;
  if (e < EE) {
    atomicAdd(&deg_out[src[e]], 1);
    atomicAdd(&deg_in[dst[e]], 1);
  }
}

// single-kernel scan: 1 block x 1024 threads, 16 nodes/thread.
__global__ __launch_bounds__(1024) void scan_all_kernel(
    const int* __restrict__ deg_in, const int* __restrict__ deg_out,
    int* __restrict__ row_ptr, int* __restrict__ cursor,
    float* __restrict__ norm_out, float* __restrict__ norm_in) {
  __shared__ int part[1024];
  int t = threadIdx.x;
  int base = t * 16;
  int loc[16];
  int s = 0;
#pragma unroll
  for (int j = 0; j < 16; ++j) { loc[j] = deg_in[base + j]; s += loc[j]; }
  part[t] = s;
  __syncthreads();
  for (int off = 1; off < 1024; off <<= 1) {
    int add = (t >= off) ? part[t - off] : 0;
    __syncthreads();
    part[t] += add;
    __syncthreads();
  }
  int run = (t == 0) ? 0 : part[t - 1];
#pragma unroll
  for (int j = 0; j < 16; ++j) {
    row_ptr[base + j] = run;
    cursor[base + j] = run;
    norm_in[base + j] = rsqrtf(fmaxf((float)loc[j], 1.0f));
    norm_out[base + j] = rsqrtf(fmaxf((float)deg_out[base + j], 1.0f));
    run += loc[j];
  }
  if (t == 1023) row_ptr[NN] = run;
}

__global__ __launch_bounds__(256) void fill_csr_kernel(
    const int* __restrict__ src, const int* __restrict__ dst,
    int* __restrict__ cursor, int* __restrict__ csr_src) {
  int e = blockIdx.x * 256 + threadIdx.x;
  if (e < EE) {
    int pos = atomicAdd(&cursor[dst[e]], 1);
    csr_src[pos] = src[e];
  }
}

// ---------------- dense GEMM: t = (h o norm_out) @ W ----------------
// 32 rows/block; A + W-chunk in LDS. INBF16: h is bf16.

template<int DIN, int DOUT, int KC, bool INBF16>
__global__ __launch_bounds__(256) void gemm_kernel(
    const void* __restrict__ hp, const float* __restrict__ W,
    const float* __restrict__ norm_out, ushort* __restrict__ tb) {
  constexpr int W4 = DOUT / 4;   // 32 or 16
  constexpr int RG = 256 / W4;   // 8 or 16 row-groups
  constexpr int RPT = 32 / RG;   // rows per thread: 4 or 2
  __shared__ float A[32][DIN];
  __shared__ float WC[KC][DOUT];
  int tid = threadIdx.x;
  int r0 = blockIdx.x * 32;
  if (INBF16) {
    constexpr int NF8 = 32 * DIN / 8;
    for (int q = tid; q < NF8; q += 256) {
      int r = q / (DIN / 8);
      int c = q % (DIN / 8);
      short8 m = *(const short8*)((const ushort*)hp + (size_t)(r0 + r) * DIN + c * 8);
      float no = norm_out[r0 + r];
#pragma unroll
      for (int i = 0; i < 8; ++i) A[r][c * 8 + i] = b2f((ushort)m[i]) * no;
    }
  } else {
    constexpr int NF4 = 32 * DIN / 4;
    for (int q = tid; q < NF4; q += 256) {
      int r = q / (DIN / 4);
      int c = q % (DIN / 4);
      float4 x = *(const float4*)((const float*)hp + (size_t)(r0 + r) * DIN + c * 4);
      float no = norm_out[r0 + r];
      x.x *= no; x.y *= no; x.z *= no; x.w *= no;
      *(float4*)&A[r][c * 4] = x;
    }
  }
  int c4 = tid % W4;
  int rg = tid / W4;
  float4 acc[RPT];
#pragma unroll
  for (int j = 0; j < RPT; ++j) acc[j] = make_float4(0.f, 0.f, 0.f, 0.f);

  for (int kc = 0; kc < DIN / KC; ++kc) {
    __syncthreads();
#pragma unroll
    for (int q = 0; q < KC * W4 / 256; ++q)
      ((float4*)WC)[q * 256 + tid] =
          ((const float4*)W)[(size_t)kc * KC * W4 + q * 256 + tid];
    __syncthreads();
#pragma unroll 4
    for (int k2 = 0; k2 < KC; ++k2) {
      float4 w = *(const float4*)&WC[k2][c4 * 4];
#pragma unroll
      for (int j = 0; j < RPT; ++j) {
        float a = A[rg + j * RG][kc * KC + k2];
        acc[j].x += a * w.x; acc[j].y += a * w.y;
        acc[j].z += a * w.z; acc[j].w += a * w.w;
      }
    }
  }
#pragma unroll
  for (int j = 0; j < RPT; ++j) {
    size_t row = (size_t)(r0 + rg + j * RG);
    ushort4 o;
    o.x = f2b(acc[j].x); o.y = f2b(acc[j].y);
    o.z = f2b(acc[j].z); o.w = f2b(acc[j].w);
    *(ushort4*)&tb[row * DOUT + c4 * 4] = o;
  }
}

// ---------------- gather: one node/block, shfl reduce (short critical path)
// out[v] = act(norm_in[v] * sum_src t[src] + b). bf16 in; bf16 out
// (+ optional fp32 z). In-wave slot reduce via __shfl_xor (no barriers),
// single cross-wave LDS stage (1 barrier). Direct csr loads.

template<int DOUT, bool RELU, bool WRITEZ>
__global__ __launch_bounds__(256) void gather_kernel(
    const ushort* __restrict__ t, const float* __restrict__ bias,
    const float* __restrict__ norm_in, const int* __restrict__ row_ptr,
    const int* __restrict__ csr, ushort* __restrict__ outb,
    float* __restrict__ zout) {
  constexpr int G8 = DOUT / 8;   // 16 (D=128) or 8 (D=64)
  constexpr int S = 256 / G8;    // 16 or 32 edge slots
  __shared__ float red[4][G8][8];
  int tid = threadIdx.x;
  int c8 = tid % G8, slot = tid / G8;
  int lane = tid & 63, w = tid >> 6;
  int v = blockIdx.x;
  int k0 = row_ptr[v], k1 = row_ptr[v + 1];
  float a[8];
#pragma unroll
  for (int i = 0; i < 8; ++i) a[i] = 0.f;
  for (int k = k0 + slot; k < k1; k += 2 * S) {
    int s0 = csr[k];
    int kb = k + S;
    bool h2 = kb < k1;
    int s1 = h2 ? csr[kb] : s0;
    short8 m0 = *(const short8*)&t[(size_t)s0 * DOUT + c8 * 8];
    short8 m1 = *(const short8*)&t[(size_t)s1 * DOUT + c8 * 8];
#pragma unroll
    for (int i = 0; i < 8; ++i) a[i] += b2f((ushort)m0[i]);
    if (h2) {
#pragma unroll
      for (int i = 0; i < 8; ++i) a[i] += b2f((ushort)m1[i]);
    }
  }
  // in-wave reduce over slot bits (lane bits G8..32): no barriers
#pragma unroll
  for (int m = G8; m < 64; m <<= 1) {
#pragma unroll
    for (int i = 0; i < 8; ++i) a[i] += __shfl_xor(a[i], m, 64);
  }
  // cross-wave: lane<G8 of each wave holds the wave partial
  if (lane < G8) {
#pragma unroll
    for (int i = 0; i < 8; ++i) red[w][lane][i] = a[i];
  }
  __syncthreads();
  if (tid < G8) {
    float ni = norm_in[v];
    float o[8];
#pragma unroll
    for (int i = 0; i < 8; ++i) {
      o[i] = (red[0][tid][i] + red[1][tid][i] + red[2][tid][i] +
              red[3][tid][i]) * ni + bias[tid * 8 + i];
      if (RELU) o[i] = fmaxf(o[i], 0.f);
    }
    ushort4 b0, b1;
    b0.x = f2b(o[0]); b0.y = f2b(o[1]); b0.z = f2b(o[2]); b0.w = f2b(o[3]);
    b1.x = f2b(o[4]); b1.y = f2b(o[5]); b1.z = f2b(o[6]); b1.w = f2b(o[7]);
    ushort* op = outb + (size_t)v * DOUT + tid * 8;
    *(ushort4*)op = b0;
    *(ushort4*)(op + 4) = b1;
    if (WRITEZ) {
      float* zp = zout + (size_t)v * DOUT + tid * 8;
      *(float4*)zp = make_float4(o[0], o[1], o[2], o[3]);
      *(float4*)(zp + 4) = make_float4(o[4], o[5], o[6], o[7]);
    }
  }
}

// ---------------- adjacency: C = sigmoid(zb @ zb^T) via bf16 MFMA --------
// R8-proven: 128x128 tile, operand-swapped MFMA, LDS-transpose epilogue.

__global__ __launch_bounds__(256) void adj_mfma_kernel(
    const ushort* __restrict__ zb, float* __restrict__ C) {
  __shared__ ushort SMEM[2 * 128 * 64];  // 32 KB: staging, then epilogue scratch
  ushort* ZR = SMEM;
  ushort* ZC = SMEM + 128 * 64;
  int t = threadIdx.x;
  int bx = blockIdx.x & 127, by = blockIdx.x >> 7;
  int row0 = by * 128, col0 = bx * 128;
  {
    int r = t >> 1;
    int ub = (t & 1) * 4;
    const float4* zr = (const float4*)(zb + (size_t)(row0 + r) * 64);
    const float4* zc = (const float4*)(zb + (size_t)(col0 + r) * 64);
    float4* LR = (float4*)ZR;
    float4* LC = (float4*)ZC;
#pragma unroll
    for (int u = 0; u < 4; ++u) {
      int sw = (ub + u) ^ (r & 7);
      LR[r * 8 + sw] = zr[ub + u];
      LC[r * 8 + sw] = zc[ub + u];
    }
  }
  __syncthreads();
  int l = t & 63, w = t >> 6;
  int wy = w >> 1, wx = w & 1;
  int lr = l & 15, lg = l >> 4;
  f32x4 acc[4][4];
#pragma unroll
  for (int i = 0; i < 4; ++i)
#pragma unroll
    for (int j = 0; j < 4; ++j) acc[i][j] = (f32x4){0.f, 0.f, 0.f, 0.f};

#pragma unroll
  for (int ks = 0; ks < 2; ++ks) {
    short8 af[4], bf_[4];
    int u = ks * 4 + lg;
#pragma unroll
    for (int i = 0; i < 4; ++i) {
      int ar = wy * 64 + i * 16 + lr;
      af[i] = *(const short8*)&ZR[ar * 64 + ((u ^ (ar & 7)) << 3)];
      int ac = wx * 64 + i * 16 + lr;
      bf_[i] = *(const short8*)&ZC[ac * 64 + ((u ^ (ac & 7)) << 3)];
    }
    // swapped operands: n'=lane&15 -> C-row, m'=(lane>>4)*4+reg -> C-col
#pragma unroll
    for (int i = 0; i < 4; ++i)
#pragma unroll
      for (int j = 0; j < 4; ++j)
        acc[i][j] = __builtin_amdgcn_mfma_f32_16x16x32_bf16(
            bf_[j], af[i], acc[i][j], 0, 0, 0);
  }

  // ---- epilogue: per-wave LDS transpose, coalesced row stores ----
  __syncthreads();
  float* scr = ((float*)SMEM) + w * (16 * 68);  // per-wave 16x68 f32
  int sr = l >> 4;            // 0..3
  int sc = (l & 15) * 4;      // 0..60
  float* Cbase = C + (size_t)(row0 + wy * 64) * NN + col0 + wx * 64 + sc;
#pragma unroll
  for (int i = 0; i < 4; ++i) {
#pragma unroll
    for (int j = 0; j < 4; ++j) {
      f32x4 o;
      o[0] = __builtin_amdgcn_rcpf(1.0f + __expf(-acc[i][j][0]));
      o[1] = __builtin_amdgcn_rcpf(1.0f + __expf(-acc[i][j][1]));
      o[2] = __builtin_amdgcn_rcpf(1.0f + __expf(-acc[i][j][2]));
      o[3] = __builtin_amdgcn_rcpf(1.0f + __expf(-acc[i][j][3]));
      *(f32x4*)&scr[lr * 68 + j * 16 + lg * 4] = o;
    }
    __syncthreads();
#pragma unroll
    for (int rp = 0; rp < 4; ++rp) {
      int rloc = rp * 4 + sr;
      float4 v = *(const float4*)&scr[rloc * 68 + sc];
      *(float4*)&Cbase[(size_t)(i * 16 + rloc) * NN] = v;
    }
    __syncthreads();
  }
}

// ---------------- launch ----------------

extern "C" void kernel_launch(void* const* d_in, const int* in_sizes, int n_in,
                              void* d_out, int out_size, void* d_ws, size_t ws_size,
                              hipStream_t stream) {
  const float* features = (const float*)d_in[0];
  const int* src = (const int*)d_in[1];
  const int* dst = (const int*)d_in[2];
  const float* W1 = (const float*)d_in[3];
  const float* b1 = (const float*)d_in[4];
  const float* W2 = (const float*)d_in[5];
  const float* b2 = (const float*)d_in[6];
  const float* W3 = (const float*)d_in[7];
  const float* b3 = (const float*)d_in[8];

  float* outp = (float*)d_out;
  float* adj = outp;                      // [N, N]
  float* z = outp + (size_t)NN * NN;      // [N, 64]

  // scratch inside adj — all DEAD before adj_mfma launches:
  ushort* tb = (ushort*)adj;              // N*128 bf16 (4 MB): t1/t2/t3
  ushort* hb = (ushort*)(adj + (size_t)NN * 64);  // N*128 bf16: h1/h2

  float* wsf = (float*)d_ws;
  float* norm_out = wsf;                  // N
  float* norm_in = wsf + NN;              // N
  int* deg_out = (int*)(wsf + 2 * NN);    // N
  int* deg_in = deg_out + NN;             // N
  int* row_ptr = deg_in + NN;             // N+1 (+pad)
  int* cursor = row_ptr + NN + 256;       // N
  int* csr_src = cursor + NN;             // E
  ushort* zb = (ushort*)(csr_src + EE);   // N*64 bf16 — in d_ws (adj reads it)

  hipMemsetAsync(deg_out, 0, 2 * NN * sizeof(int), stream);
  count_deg_kernel<<<EE / 256, 256, 0, stream>>>(src, dst, deg_out, deg_in);
  scan_all_kernel<<<1, 1024, 0, stream>>>(deg_in, deg_out, row_ptr, cursor,
                                          norm_out, norm_in);
  fill_csr_kernel<<<EE / 256, 256, 0, stream>>>(src, dst, cursor, csr_src);

  // layer 1: t1 = (x o n)W1 (bf16); h1 = relu(agg o n_in + b1) (bf16)
  gemm_kernel<D0, D1, 32, false><<<NN / 32, 256, 0, stream>>>(
      features, W1, norm_out, tb);
  gather_kernel<D1, true, false><<<NN, 256, 0, stream>>>(
      tb, b1, norm_in, row_ptr, csr_src, hb, nullptr);
  // layer 2
  gemm_kernel<D1, D1, 64, true><<<NN / 32, 256, 0, stream>>>(
      hb, W2, norm_out, tb);
  gather_kernel<D1, true, false><<<NN, 256, 0, stream>>>(
      tb, b2, norm_in, row_ptr, csr_src, hb, nullptr);
  // layer 3 (no relu): t3 bf16; gather writes zb bf16 + z fp32
  gemm_kernel<D1, D2, 64, true><<<NN / 32, 256, 0, stream>>>(
      hb, W3, norm_out, tb);
  gather_kernel<D2, false, true><<<NN, 256, 0, stream>>>(
      tb, b3, norm_in, row_ptr, csr_src, zb, z);

  adj_mfma_kernel<<<(NN / 128) * (NN / 128), 256, 0, stream>>>(zb, adj);
}

// Round 16
// 391.409 us; speedup vs baseline: 1.0211x; 1.0067x over previous
//
#include <hip/hip_runtime.h>
#include <hip/hip_bf16.h>

#define NN 16384
#define EE 524288

constexpr int D0 = 256, D1 = 128, D2 = 64;

typedef __attribute__((ext_vector_type(8))) short short8;
typedef __attribute__((ext_vector_type(4))) float f32x4;

__device__ __forceinline__ float b2f(ushort u) {
  union { unsigned int i; float f; } x;
  x.i = ((unsigned int)u) << 16;
  return x.f;
}
__device__ __forceinline__ ushort f2b(float f) {
  __hip_bfloat16 h = __float2bfloat16(f);
  return *reinterpret_cast<ushort*>(&h);
}

// ---------------- fused: count_deg (blocks 0..2047) || GEMM1 (2048..3071) --
// GEMM1 computes t1 = features @ W1 (NO norm_out — applied per-edge in
// gather1 instead), so it has no dependency on the degree counting.

__global__ __launch_bounds__(256) void count_gemm1_kernel(
    const int* __restrict__ src, const int* __restrict__ dst,
    int* __restrict__ deg_out, int* __restrict__ deg_in,
    const float* __restrict__ features, const float* __restrict__ W1,
    ushort* __restrict__ t1) {
  __shared__ float A[16][D0];    // 16 KB
  __shared__ float WC[32][D1];   // 16 KB
  int tid = threadIdx.x;
  int b = blockIdx.x;
  if (b < 2048) {
    int e = b * 256 + tid;       // 2048*256 == EE exactly
    atomicAdd(&deg_out[src[e]], 1);
    atomicAdd(&deg_in[dst[e]], 1);
    return;
  }
  int r0 = (b - 2048) * 16;
  for (int q = tid; q < 16 * D0 / 4; q += 256) {
    int r = q / (D0 / 4), c = q % (D0 / 4);
    *(float4*)&A[r][c * 4] =
        *(const float4*)&features[(size_t)(r0 + r) * D0 + c * 4];
  }
  int c4 = tid % 32;   // W4 = D1/4 = 32
  int rg = tid / 32;   // 8 row-groups, 2 rows each
  float4 acc[2];
  acc[0] = make_float4(0.f, 0.f, 0.f, 0.f);
  acc[1] = make_float4(0.f, 0.f, 0.f, 0.f);
  for (int kc = 0; kc < D0 / 32; ++kc) {
    __syncthreads();
    for (int q = tid; q < 32 * 32; q += 256)
      ((float4*)WC)[q] = ((const float4*)(W1 + (size_t)kc * 32 * D1))[q];
    __syncthreads();
#pragma unroll 4
    for (int k2 = 0; k2 < 32; ++k2) {
      float4 w = *(const float4*)&WC[k2][c4 * 4];
#pragma unroll
      for (int j = 0; j < 2; ++j) {
        float a = A[rg + j * 8][kc * 32 + k2];
        acc[j].x += a * w.x; acc[j].y += a * w.y;
        acc[j].z += a * w.z; acc[j].w += a * w.w;
      }
    }
  }
#pragma unroll
  for (int j = 0; j < 2; ++j) {
    size_t row = (size_t)(r0 + rg + j * 8);
    ushort4 o;
    o.x = f2b(acc[j].x); o.y = f2b(acc[j].y);
    o.z = f2b(acc[j].z); o.w = f2b(acc[j].w);
    *(ushort4*)&t1[row * D1 + c4 * 4] = o;
  }
}

// ---------------- parallel 3-stage scan (R12-proven) ----------------

__global__ __launch_bounds__(256) void scan1_kernel(
    const int* __restrict__ deg_in, int* __restrict__ intra,
    int* __restrict__ part) {
  __shared__ int sc[256];
  int t = threadIdx.x;
  int v = blockIdx.x * 256 + t;
  int d = deg_in[v];
  sc[t] = d;
  __syncthreads();
  for (int off = 1; off < 256; off <<= 1) {
    int add = (t >= off) ? sc[t - off] : 0;
    __syncthreads();
    sc[t] += add;
    __syncthreads();
  }
  intra[v] = sc[t] - d;
  if (t == 255) part[blockIdx.x] = sc[255];
}

__global__ __launch_bounds__(64) void scan2_kernel(
    const int* __restrict__ part, int* __restrict__ partx) {
  __shared__ int p[64];
  int t = threadIdx.x;
  int d = part[t];
  p[t] = d;
  __syncthreads();
  for (int off = 1; off < 64; off <<= 1) {
    int add = (t >= off) ? p[t - off] : 0;
    __syncthreads();
    p[t] += add;
    __syncthreads();
  }
  partx[t] = p[t] - d;
}

__global__ __launch_bounds__(256) void scan3_kernel(
    const int* __restrict__ deg_in, const int* __restrict__ deg_out,
    const int* __restrict__ intra, const int* __restrict__ partx,
    int* __restrict__ row_ptr, int* __restrict__ cursor,
    float* __restrict__ norm_out, float* __restrict__ norm_in) {
  int t = threadIdx.x;
  int v = blockIdx.x * 256 + t;
  int rp = partx[blockIdx.x] + intra[v];
  row_ptr[v] = rp;
  cursor[v] = rp;
  norm_out[v] = rsqrtf(fmaxf((float)deg_out[v], 1.0f));
  norm_in[v]  = rsqrtf(fmaxf((float)deg_in[v], 1.0f));
  if (v == NN - 1) row_ptr[NN] = rp + deg_in[v];
}

__global__ __launch_bounds__(256) void fill_csr_kernel(
    const int* __restrict__ src, const int* __restrict__ dst,
    int* __restrict__ cursor, int* __restrict__ csr_src) {
  int e = blockIdx.x * 256 + threadIdx.x;
  if (e < EE) {
    int pos = atomicAdd(&cursor[dst[e]], 1);
    csr_src[pos] = src[e];
  }
}

// ---------------- dense GEMM (layers 2/3): t = (h o norm_out) @ W --------

template<int DIN, int DOUT, int KC, bool OBF16>
__global__ __launch_bounds__(256) void gemm_kernel(
    const float* __restrict__ h, const float* __restrict__ W,
    const float* __restrict__ norm_out, float* __restrict__ tf,
    ushort* __restrict__ tb) {
  constexpr int W4 = DOUT / 4;
  constexpr int RG = 256 / W4;
  constexpr int RPT = 32 / RG;
  __shared__ float A[32][DIN];
  __shared__ float WC[KC][DOUT];
  int tid = threadIdx.x;
  int r0 = blockIdx.x * 32;
  constexpr int NF4 = 32 * DIN / 4;
  for (int q = tid; q < NF4; q += 256) {
    int r = q / (DIN / 4);
    int c = q % (DIN / 4);
    float4 x = *(const float4*)&h[(size_t)(r0 + r) * DIN + c * 4];
    float no = norm_out[r0 + r];
    x.x *= no; x.y *= no; x.z *= no; x.w *= no;
    *(float4*)&A[r][c * 4] = x;
  }
  int c4 = tid % W4;
  int rg = tid / W4;
  float4 acc[RPT];
#pragma unroll
  for (int j = 0; j < RPT; ++j) acc[j] = make_float4(0.f, 0.f, 0.f, 0.f);

  for (int kc = 0; kc < DIN / KC; ++kc) {
    __syncthreads();
#pragma unroll
    for (int q = 0; q < KC * W4 / 256; ++q)
      ((float4*)WC)[q * 256 + tid] =
          ((const float4*)W)[(size_t)kc * KC * W4 + q * 256 + tid];
    __syncthreads();
#pragma unroll 4
    for (int k2 = 0; k2 < KC; ++k2) {
      float4 w = *(const float4*)&WC[k2][c4 * 4];
#pragma unroll
      for (int j = 0; j < RPT; ++j) {
        float a = A[rg + j * RG][kc * KC + k2];
        acc[j].x += a * w.x; acc[j].y += a * w.y;
        acc[j].z += a * w.z; acc[j].w += a * w.w;
      }
    }
  }
#pragma unroll
  for (int j = 0; j < RPT; ++j) {
    size_t row = (size_t)(r0 + rg + j * RG);
    if (OBF16) {
      ushort4 o;
      o.x = f2b(acc[j].x); o.y = f2b(acc[j].y);
      o.z = f2b(acc[j].z); o.w = f2b(acc[j].w);
      *(ushort4*)&tb[row * DOUT + c4 * 4] = o;
    } else {
      *(float4*)&tf[row * DOUT + c4 * 4] = acc[j];
    }
  }
}

// ---------------- gather (bf16 t): out fp32. SRCNORM: msg *= norm_out[src]

template<int DOUT, bool RELU, bool SRCNORM>
__global__ __launch_bounds__(256) void gather_bf16_kernel(
    const ushort* __restrict__ t, const float* __restrict__ bias,
    const float* __restrict__ norm_out, const float* __restrict__ norm_in,
    const int* __restrict__ row_ptr, const int* __restrict__ csr,
    float* __restrict__ out) {
  constexpr int G8 = DOUT / 8;   // 16
  constexpr int S = 256 / G8;    // 16
  __shared__ float red[S][G8][8];
  int tid = threadIdx.x;
  int c8 = tid % G8, slot = tid / G8;
  int v = blockIdx.x;
  int k0 = row_ptr[v], k1 = row_ptr[v + 1];
  float a[8];
#pragma unroll
  for (int i = 0; i < 8; ++i) a[i] = 0.f;
  for (int k = k0 + slot; k < k1; k += S) {
    int s = csr[k];
    short8 m = *(const short8*)&t[(size_t)s * DOUT + c8 * 8];
    if (SRCNORM) {
      float no = norm_out[s];
#pragma unroll
      for (int i = 0; i < 8; ++i) a[i] += b2f((ushort)m[i]) * no;
    } else {
#pragma unroll
      for (int i = 0; i < 8; ++i) a[i] += b2f((ushort)m[i]);
    }
  }
#pragma unroll
  for (int i = 0; i < 8; ++i) red[slot][c8][i] = a[i];
  __syncthreads();
#pragma unroll
  for (int s = S / 2; s >= 1; s >>= 1) {
    if (slot < s) {
#pragma unroll
      for (int i = 0; i < 8; ++i) red[slot][c8][i] += red[slot + s][c8][i];
    }
    __syncthreads();
  }
  if (tid < G8) {
    float ni = norm_in[v];
    float o[8];
#pragma unroll
    for (int i = 0; i < 8; ++i) {
      o[i] = red[0][tid][i] * ni + bias[tid * 8 + i];
      if (RELU) o[i] = fmaxf(o[i], 0.f);
    }
    *(float4*)&out[(size_t)v * DOUT + tid * 8] = make_float4(o[0], o[1], o[2], o[3]);
    *(float4*)&out[(size_t)v * DOUT + tid * 8 + 4] = make_float4(o[4], o[5], o[6], o[7]);
  }
}

// ---------------- gather (fp32 t), layer 3: writes z fp32 + zb bf16 ------

template<int DOUT, bool RELU>
__global__ __launch_bounds__(256) void gather_f32_kernel(
    const float* __restrict__ t, const float* __restrict__ bias,
    const float* __restrict__ norm_in, const int* __restrict__ row_ptr,
    const int* __restrict__ csr, float* __restrict__ out,
    ushort* __restrict__ zb) {
  constexpr int W4 = DOUT / 4;   // 16
  constexpr int S = 256 / W4;    // 16
  __shared__ float4 red[256];
  int tid = threadIdx.x;
  int c4 = tid % W4, slot = tid / W4;
  int v = blockIdx.x;
  int k0 = row_ptr[v], k1 = row_ptr[v + 1];
  float4 acc = make_float4(0.f, 0.f, 0.f, 0.f);
  for (int k = k0 + slot; k < k1; k += S) {
    int s = csr[k];
    float4 m = *(const float4*)&t[(size_t)s * DOUT + c4 * 4];
    acc.x += m.x; acc.y += m.y; acc.z += m.z; acc.w += m.w;
  }
  red[tid] = acc;
  __syncthreads();
  if (tid < W4) {
    float4 a = red[tid];
#pragma unroll
    for (int s = 1; s < S; ++s) {
      float4 b = red[s * W4 + tid];
      a.x += b.x; a.y += b.y; a.z += b.z; a.w += b.w;
    }
    float ni = norm_in[v];
    float4 b4 = *(const float4*)&bias[tid * 4];
    a.x = a.x * ni + b4.x; a.y = a.y * ni + b4.y;
    a.z = a.z * ni + b4.z; a.w = a.w * ni + b4.w;
    if (RELU) {
      a.x = fmaxf(a.x, 0.f); a.y = fmaxf(a.y, 0.f);
      a.z = fmaxf(a.z, 0.f); a.w = fmaxf(a.w, 0.f);
    }
    *(float4*)&out[(size_t)v * DOUT + tid * 4] = a;
    ushort4 ob;
    ob.x = f2b(a.x); ob.y = f2b(a.y); ob.z = f2b(a.z); ob.w = f2b(a.w);
    *(ushort4*)&zb[(size_t)v * DOUT + tid * 4] = ob;
  }
}

// ---------------- adjacency: C = sigmoid(zb @ zb^T) via bf16 MFMA --------
// R8-proven: 128x128 tile, operand-swapped MFMA, LDS-transpose epilogue.

__global__ __launch_bounds__(256) void adj_mfma_kernel(
    const ushort* __restrict__ zb, float* __restrict__ C) {
  __shared__ ushort SMEM[2 * 128 * 64];
  ushort* ZR = SMEM;
  ushort* ZC = SMEM + 128 * 64;
  int t = threadIdx.x;
  int bx = blockIdx.x & 127, by = blockIdx.x >> 7;
  int row0 = by * 128, col0 = bx * 128;
  {
    int r = t >> 1;
    int ub = (t & 1) * 4;
    const float4* zr = (const float4*)(zb + (size_t)(row0 + r) * 64);
    const float4* zc = (const float4*)(zb + (size_t)(col0 + r) * 64);
    float4* LR = (float4*)ZR;
    float4* LC = (float4*)ZC;
#pragma unroll
    for (int u = 0; u < 4; ++u) {
      int sw = (ub + u) ^ (r & 7);
      LR[r * 8 + sw] = zr[ub + u];
      LC[r * 8 + sw] = zc[ub + u];
    }
  }
  __syncthreads();
  int l = t & 63, w = t >> 6;
  int wy = w >> 1, wx = w & 1;
  int lr = l & 15, lg = l >> 4;
  f32x4 acc[4][4];
#pragma unroll
  for (int i = 0; i < 4; ++i)
#pragma unroll
    for (int j = 0; j < 4; ++j) acc[i][j] = (f32x4){0.f, 0.f, 0.f, 0.f};

#pragma unroll
  for (int ks = 0; ks < 2; ++ks) {
    short8 af[4], bf_[4];
    int u = ks * 4 + lg;
#pragma unroll
    for (int i = 0; i < 4; ++i) {
      int ar = wy * 64 + i * 16 + lr;
      af[i] = *(const short8*)&ZR[ar * 64 + ((u ^ (ar & 7)) << 3)];
      int ac = wx * 64 + i * 16 + lr;
      bf_[i] = *(const short8*)&ZC[ac * 64 + ((u ^ (ac & 7)) << 3)];
    }
    // swapped operands: n'=lane&15 -> C-row, m'=(lane>>4)*4+reg -> C-col
#pragma unroll
    for (int i = 0; i < 4; ++i)
#pragma unroll
      for (int j = 0; j < 4; ++j)
        acc[i][j] = __builtin_amdgcn_mfma_f32_16x16x32_bf16(
            bf_[j], af[i], acc[i][j], 0, 0, 0);
  }

  __syncthreads();
  float* scr = ((float*)SMEM) + w * (16 * 68);
  int sr = l >> 4;
  int sc = (l & 15) * 4;
  float* Cbase = C + (size_t)(row0 + wy * 64) * NN + col0 + wx * 64 + sc;
#pragma unroll
  for (int i = 0; i < 4; ++i) {
#pragma unroll
    for (int j = 0; j < 4; ++j) {
      f32x4 o;
      o[0] = __builtin_amdgcn_rcpf(1.0f + __expf(-acc[i][j][0]));
      o[1] = __builtin_amdgcn_rcpf(1.0f + __expf(-acc[i][j][1]));
      o[2] = __builtin_amdgcn_rcpf(1.0f + __expf(-acc[i][j][2]));
      o[3] = __builtin_amdgcn_rcpf(1.0f + __expf(-acc[i][j][3]));
      *(f32x4*)&scr[lr * 68 + j * 16 + lg * 4] = o;
    }
    __syncthreads();
#pragma unroll
    for (int rp = 0; rp < 4; ++rp) {
      int rloc = rp * 4 + sr;
      float4 v = *(const float4*)&scr[rloc * 68 + sc];
      *(float4*)&Cbase[(size_t)(i * 16 + rloc) * NN] = v;
    }
    __syncthreads();
  }
}

// ---------------- launch ----------------

extern "C" void kernel_launch(void* const* d_in, const int* in_sizes, int n_in,
                              void* d_out, int out_size, void* d_ws, size_t ws_size,
                              hipStream_t stream) {
  const float* features = (const float*)d_in[0];
  const int* src = (const int*)d_in[1];
  const int* dst = (const int*)d_in[2];
  const float* W1 = (const float*)d_in[3];
  const float* b1 = (const float*)d_in[4];
  const float* W2 = (const float*)d_in[5];
  const float* b2 = (const float*)d_in[6];
  const float* W3 = (const float*)d_in[7];
  const float* b3 = (const float*)d_in[8];

  float* outp = (float*)d_out;
  float* adj = outp;                      // [N, N]
  float* z = outp + (size_t)NN * NN;      // [N, 64]

  // scratch inside adj — all DEAD before adj_mfma launches:
  ushort* tb = (ushort*)adj;              // N*128 bf16 (4 MB): t1/t2
  float* hbuf = adj + (size_t)NN * 64;    // N*128 fp32: h1/h2
  float* t3 = adj + (size_t)NN * 192;     // N*64 fp32

  float* wsf = (float*)d_ws;
  float* norm_out = wsf;                  // N
  float* norm_in = wsf + NN;              // N
  int* deg_out = (int*)(wsf + 2 * NN);    // N
  int* deg_in = deg_out + NN;             // N
  int* row_ptr = deg_in + NN;             // N+1 (+pad)
  int* cursor = row_ptr + NN + 256;       // N
  int* csr_src = cursor + NN;             // E
  ushort* zb = (ushort*)(csr_src + EE);   // N*64 bf16
  int* intra = (int*)(zb + (size_t)NN * 64);  // N
  int* part = intra + NN;                 // 64
  int* partx = part + 64;                 // 64

  hipMemsetAsync(deg_out, 0, 2 * NN * sizeof(int), stream);
  // fused: degree counting (2048 blocks) || GEMM1 no-norm (1024 blocks)
  count_gemm1_kernel<<<3072, 256, 0, stream>>>(
      src, dst, deg_out, deg_in, features, W1, tb);
  scan1_kernel<<<64, 256, 0, stream>>>(deg_in, intra, part);
  scan2_kernel<<<1, 64, 0, stream>>>(part, partx);
  scan3_kernel<<<64, 256, 0, stream>>>(deg_in, deg_out, intra, partx,
                                       row_ptr, cursor, norm_out, norm_in);
  fill_csr_kernel<<<EE / 256, 256, 0, stream>>>(src, dst, cursor, csr_src);

  // layer 1: gather applies norm_out[src] per edge (SRCNORM)
  gather_bf16_kernel<D1, true, true><<<NN, 256, 0, stream>>>(
      tb, b1, norm_out, norm_in, row_ptr, csr_src, hbuf);
  // layer 2
  gemm_kernel<D1, D1, 64, true><<<NN / 32, 256, 0, stream>>>(
      hbuf, W2, norm_out, nullptr, tb);
  gather_bf16_kernel<D1, true, false><<<NN, 256, 0, stream>>>(
      tb, b2, norm_out, norm_in, row_ptr, csr_src, hbuf);
  // layer 3 (no relu): t3 fp32 -> z fp32 + zb bf16
  gemm_kernel<D1, D2, 64, false><<<NN / 32, 256, 0, stream>>>(
      hbuf, W3, norm_out, t3, nullptr);
  gather_f32_kernel<D2, false><<<NN, 256, 0, stream>>>(
      t3, b3, norm_in, row_ptr, csr_src, z, zb);

  adj_mfma_kernel<<<(NN / 128) * (NN / 128), 256, 0, stream>>>(zb, adj);
}